// Round 16
// baseline (121.218 us; speedup 1.0000x reference)
//
#include <hip/hip_runtime.h>
#include <hip/hip_bf16.h>
#include <stdint.h>
#include <stddef.h>

// NT-Xent loss, B=4096, D=256, N=8192, T=0.5.
// normalize(+zero sumexp/ticket) -> fused symmetric ZZ^T GEMM + exp
// row/col-sum + positive capture + LAST-BLOCK finalize/mean. 2 dispatches.
//
// R20 (resubmit; R15 bench was a GPUAcquisitionTimeout, no data):
// TICKET-FUSED FINALIZE. R19 (90.02 us, best) showed the reduce
// kernel's cost was launch+gap (~2-3 us), not work (8192 logs = trivial).
// Fold finalize into simexp without grid.sync (R17: coop sync cost ~40us):
// every thread __threadfence() (release of its sumexp atomics + plain pos
// stores) -> __syncthreads -> tid0 atomicAdd(ticket); the block drawing
// 255 re-fences and reduces all 8192 rows via __hip_atomic_load(AGENT)
// (bypasses stale per-XCD caches, guide G16), writes out[0] directly.
// ticket in d_ws, zeroed by normalize (stream-ordered).
// Core frozen at R14 (five null attacks: R12/R15/R16/R18 barriers, vmcnt,
// LDS volume, occupancy): 8 waves in 4x2 (wave = 32r x 64c), af[2][8]
// LDS-bounce-pinned, quadrant phases with deferred epilogue slices (q3
// carried one tile), 1 __syncthreads/tile, XOR-swizzled LDS (swizzle on
// global source), symmetry (2080 unordered 128x128 tile-pairs), balanced
// tail (s=32 halves on cj2/cj3), prologue vmcnt(8), exp-scale folded into
// normalize (zn *= sqrt(2/ln2): e = exp2(dot'), pos = dot'*ln2).

#define B_ROWS 4096
#define D_DIM  256
#define N_ROWS 8192
#define BM 128
#define BN 128

typedef __bf16 bf16;
typedef bf16  bf16x8  __attribute__((ext_vector_type(8)));
typedef bf16  bf16x4  __attribute__((ext_vector_type(4)));
typedef float floatx4 __attribute__((ext_vector_type(4)));

// ---------------------------------------------------------------- normalize
// One wave per row: 256 fp32 -> L2-normalized bf16 scaled by sqrt(2/ln2)
// so dot' = (2/ln2)*dot and e = exp2(dot'). Zeroes sumexp; zeroes ticket.
__global__ __launch_bounds__(256) void normalize_kernel(
    const float* __restrict__ z_i, const float* __restrict__ z_j,
    bf16* __restrict__ zn, float* __restrict__ sumexp,
    unsigned* __restrict__ ticket) {
  const int wave = threadIdx.x >> 6;
  const int lane = threadIdx.x & 63;
  const int row  = blockIdx.x * 4 + wave;
  if (blockIdx.x == 0 && threadIdx.x == 0) *ticket = 0u;
  const float* src = (row < B_ROWS) ? (z_i + (size_t)row * D_DIM)
                                    : (z_j + (size_t)(row - B_ROWS) * D_DIM);
  float4 v = ((const float4*)src)[lane];
  float ss = v.x * v.x + v.y * v.y + v.z * v.z + v.w * v.w;
  #pragma unroll
  for (int m = 1; m < 64; m <<= 1) ss += __shfl_xor(ss, m);
  const float rn = rsqrtf(ss) * 1.6986436f;  // * sqrt(2/ln2)
  bf16x4 o;
  o[0] = (bf16)(v.x * rn);
  o[1] = (bf16)(v.y * rn);
  o[2] = (bf16)(v.z * rn);
  o[3] = (bf16)(v.w * rn);
  ((bf16x4*)(zn + (size_t)row * D_DIM))[lane] = o;
  if (lane == 0) sumexp[row] = 0.f;
}

// ------------------------------------------------------- fused sim+exp+sum
// Grid: 64 ri x 4 cj = 256 blocks (1/CU by 128 KB LDS). Block (ri,cj): 8
// tiles s=8cj+t; (ri<32, cj>=2) add the j64-half (cj-2) of s=32 (tail).
// 8 waves in 4x2 (wave = 32 rows x 64 cols); quadrant phases (16 cols x
// full K = 16 MFMA), finished quadrant's exp/sum slice overlaps the next
// quadrant's MFMAs; q3 carried one tile. LDS XOR-swizzled (swizzle on the
// GLOBAL source address; LDS dest linear). Last block finalizes.
__global__ __launch_bounds__(512, 2) void simexp_kernel(
    const bf16* __restrict__ zn, float* __restrict__ sumexp,
    float* __restrict__ pos, unsigned* __restrict__ ticket,
    float* __restrict__ out) {
  __shared__ __align__(16) bf16 Bs[2][BN * D_DIM];  // 2 x 64 KB
  __shared__ unsigned s_last;

  const int tid   = threadIdx.x;
  const int wave  = tid >> 6;
  const int lane  = tid & 63;
  const int lcol  = lane & 15;   // MFMA: A row / B col / C col
  const int lquad = lane >> 4;   // MFMA: k-group / C row-group
  const int wr = (wave >> 1) * 32;  // wave row offset: 0,32,64,96
  const int wc = (wave & 1) * 64;   // wave col offset: 0,64
  const int ri = blockIdx.x >> 2;   // row tile 0..63
  const int cj = blockIdx.x & 3;    // s-chunk 0..3
  const int row_base = ri * BM;
  const bool has_tail = (ri < 32 && cj >= 2);

  auto ct_of = [&](int t) { return (ri + 8 * cj + t) & 63; };  // col tile

  // stage rows of a tile into Bs[buf]: chunk slot s=it*512+tid, row n=s>>5,
  // swizzled k-chunk; coalesced 16B global_load_lds, source pre-swizzled.
  auto stageB = [&](int buf, const bf16* src, int it0, int it1) {
    for (int it = it0; it < it1; ++it) {
      const int s   = it * 512 + tid;
      const int n   = s >> 5;
      const int kcs = s & 31;
      const int kc  = (kcs & 24) | ((kcs & 7) ^ (n & 7));
      __builtin_amdgcn_global_load_lds(
          (const __attribute__((address_space(1))) unsigned int*)
              (src + (size_t)n * D_DIM + kc * 8),
          (__attribute__((address_space(3))) unsigned int*)&Bs[buf][s * 8],
          16, 0, 0);
    }
  };

  // ---- prologue: A tile -> buf0, first B tile -> buf1, overlapped.
  stageB(0, zn + (size_t)row_base * D_DIM, 0, 8);
  stageB(1, zn + (size_t)ct_of(0) * BM * D_DIM, 0, 8);
  // af reads only need A: wait A's 8 loads (B0's 8 still in flight).
  asm volatile("s_waitcnt vmcnt(8)" ::: "memory");
  __builtin_amdgcn_sched_barrier(0);
  __builtin_amdgcn_s_barrier();

  // af[ti][kq]: buf0 backing overwritten later -> pinned in registers (64).
  floatx4 af[2][8];
  #pragma unroll
  for (int ti = 0; ti < 2; ++ti) {
    const int n = wr + ti * 16 + lcol;
    #pragma unroll
    for (int kq = 0; kq < 8; ++kq) {
      const int kc  = kq * 4 + lquad;
      const int kcs = (kc & 24) | ((kc & 7) ^ (n & 7));
      af[ti][kq] = *(const floatx4*)(&Bs[0][(n * 32 + kcs) * 8]);
    }
  }
  __syncthreads();  // drains B0 + af reads -> buf0 free for staging

  float rowsum[2][4];  // [ti][r]; row = wr + ti*16 + lquad*4 + r
  #pragma unroll
  for (int ti = 0; ti < 2; ++ti)
    #pragma unroll
    for (int r = 0; r < 4; ++r) rowsum[ti][r] = 0.f;

#define MFMA_(A, B_, C) __builtin_amdgcn_mfma_f32_16x16x32_bf16( \
    __builtin_bit_cast(bf16x8, A), B_, C, 0, 0, 0)

#define QPHASE(ACC, Q)                                                    \
  {                                                                       \
    bf16x8 bfr[8];                                                        \
    const int n = wc + (Q) * 16 + lcol;                                   \
    _Pragma("unroll")                                                     \
    for (int kq = 0; kq < 8; ++kq) {                                      \
      const int kc  = kq * 4 + lquad;                                     \
      const int kcs = (kc & 24) | ((kc & 7) ^ (n & 7));                   \
      bfr[kq] = *(const bf16x8*)(bbase + n * D_DIM + kcs * 8);            \
    }                                                                     \
    ACC[0] = floatx4{0.f, 0.f, 0.f, 0.f};                                 \
    ACC[1] = floatx4{0.f, 0.f, 0.f, 0.f};                                 \
    _Pragma("unroll")                                                     \
    for (int kq = 0; kq < 8; ++kq) {                                      \
      ACC[0] = MFMA_(af[0][kq], bfr[kq], ACC[0]);                         \
      ACC[1] = MFMA_(af[1][kq], bfr[kq], ACC[1]);                         \
    }                                                                     \
  }

#define SLICE(ACC, Q, CB, DG)                                             \
  {                                                                       \
    float cs = 0.f;                                                       \
    _Pragma("unroll")                                                     \
    for (int ti = 0; ti < 2; ++ti) {                                      \
      _Pragma("unroll")                                                   \
      for (int r = 0; r < 4; ++r) {                                       \
        const float v = ACC[ti][r];                                       \
        float e = __builtin_amdgcn_exp2f(v);                              \
        if (DG) {                                                         \
          const int rg = row_base + wr + ti * 16 + lquad * 4 + r;         \
          const int cg = (CB) + wc + (Q) * 16 + lcol;                     \
          if (cg == rg) e = 0.f;  /* mask self-similarity */              \
        }                                                                 \
        rowsum[ti][r] += e;                                               \
        cs += e;                                                          \
      }                                                                   \
    }                                                                     \
    cs += __shfl_xor(cs, 16);                                             \
    cs += __shfl_xor(cs, 32);                                             \
    if (!(DG) && lquad == 0)                                              \
      atomicAdd(&sumexp[(CB) + wc + (Q) * 16 + lcol], cs);                \
  }

  floatx4 a3[2];            // q3 acc, carried one tile (sliced next tile)
  int  pcol3  = 0;
  bool pdiag3 = false;

  #pragma unroll 1
  for (int t = 0; t < 8; ++t) {
    const bf16* bbase = &Bs[(t + 1) & 1][0];   // compute buffer
    const int sb = t & 1;                      // stage buffer (disjoint)
    if (t < 7) {
      stageB(sb, zn + (size_t)ct_of(t + 1) * BM * D_DIM, 0, 8);
    } else if (has_tail) {
      stageB(sb, zn + (size_t)((ri + 32) * BM + (cj - 2) * 64) * D_DIM, 0, 4);
    }
    const int  colb = ct_of(t) * BM;
    const bool diag = (cj == 0 && t == 0);

    floatx4 a0[2], a1[2], a2[2];
    QPHASE(a0, 0)
    if (t > 0) SLICE(a3, 3, pcol3, pdiag3)   // prev tile's q3, overlapped
    QPHASE(a1, 1)
    SLICE(a0, 0, colb, diag)
    QPHASE(a2, 2)
    SLICE(a1, 1, colb, diag)
    QPHASE(a3, 3)
    SLICE(a2, 2, colb, diag)
    pcol3 = colb;
    pdiag3 = diag;
    __syncthreads();  // vmcnt(0)+barrier: stage done, buffer swap safe
  }
  SLICE(a3, 3, pcol3, pdiag3)   // tile 7's q3

  // tail: j64-half (cj-2) of s=32 in buf1; positive pairs live here.
  if (has_tail && wc == 0) {
    const int colb = (ri + 32) * BM + (cj - 2) * 64;
    const bf16* bbase = &Bs[1][0];
    floatx4 ta[2];
    #pragma unroll
    for (int Q = 0; Q < 4; ++Q) {
      QPHASE(ta, Q)
      float cs = 0.f;
      #pragma unroll
      for (int ti = 0; ti < 2; ++ti) {
        #pragma unroll
        for (int r = 0; r < 4; ++r) {
          const float v = ta[ti][r];
          const float e = __builtin_amdgcn_exp2f(v);
          const int rg = row_base + wr + ti * 16 + lquad * 4 + r;
          const int cg = colb + Q * 16 + lcol;
          if (cg == rg + B_ROWS) {                    // positive pair
            const float p = v * 0.6931471805599453f;  // sim/T = v*ln2
            pos[rg] = p;
            pos[cg] = p;
          }
          rowsum[ti][r] += e;
          cs += e;
        }
      }
      cs += __shfl_xor(cs, 16);
      cs += __shfl_xor(cs, 32);
      if (lquad == 0) atomicAdd(&sumexp[colb + Q * 16 + lcol], cs);
    }
  }
#undef SLICE
#undef QPHASE
#undef MFMA_

  // rowsum: reduce 16 col-lanes, 1 atomic per row per wave
  #pragma unroll
  for (int ti = 0; ti < 2; ++ti) {
    #pragma unroll
    for (int r = 0; r < 4; ++r) {
      float s2 = rowsum[ti][r];
      s2 += __shfl_xor(s2, 1);
      s2 += __shfl_xor(s2, 2);
      s2 += __shfl_xor(s2, 4);
      s2 += __shfl_xor(s2, 8);
      if (lcol == 0) {
        const int grow = row_base + wr + ti * 16 + lquad * 4 + r;
        atomicAdd(&sumexp[grow], s2);
      }
    }
  }

  // ---------------- last-block finalize (ticket pattern) ----------------
  __threadfence();   // release: this thread's sumexp atomics + pos stores
  __syncthreads();   // whole block done (all threads fenced)
  if (tid == 0) s_last = (atomicAdd(ticket, 1u) == 255u) ? 1u : 0u;
  __syncthreads();
  if (s_last) {
    __threadfence();  // acquire side
    const float ln2 = 0.6931471805599453f;
    float s = 0.f;
    #pragma unroll
    for (int it = 0; it < 16; ++it) {
      const int k = it * 512 + tid;
      const float se = __hip_atomic_load(&sumexp[k], __ATOMIC_RELAXED,
                                         __HIP_MEMORY_SCOPE_AGENT);
      const float pp = __hip_atomic_load(&pos[k], __ATOMIC_RELAXED,
                                         __HIP_MEMORY_SCOPE_AGENT);
      s += __builtin_amdgcn_logf(se) * ln2 - pp;  // log2(se)*ln2 = ln(se)
    }
    #pragma unroll
    for (int m = 1; m < 64; m <<= 1) s += __shfl_xor(s, m);
    float* ws = (float*)&Bs[0][0];  // LDS reuse (post-loop, block-synced)
    if (lane == 0) ws[wave] = s;
    __syncthreads();
    if (wave == 0) {
      float tt = (lane < 8) ? ws[lane] : 0.f;
      #pragma unroll
      for (int m = 1; m < 8; m <<= 1) tt += __shfl_xor(tt, m);
      if (lane == 0) out[0] = tt * (1.0f / N_ROWS);
    }
  }
}

extern "C" void kernel_launch(void* const* d_in, const int* in_sizes, int n_in,
                              void* d_out, int out_size, void* d_ws,
                              size_t ws_size, hipStream_t stream) {
  const float* z_i = (const float*)d_in[0];
  const float* z_j = (const float*)d_in[1];
  float* out = (float*)d_out;

  // workspace: zn (4 MB bf16) | sumexp (32 KB) | pos (32 KB) | ticket (4 B)
  bf16* zn = (bf16*)d_ws;
  float* sumexp = (float*)((char*)d_ws + (size_t)N_ROWS * D_DIM * sizeof(bf16));
  float* pos = sumexp + N_ROWS;
  unsigned* ticket = (unsigned*)(pos + N_ROWS);

  normalize_kernel<<<N_ROWS / 4, 256, 0, stream>>>(z_i, z_j, zn, sumexp,
                                                   ticket);
  simexp_kernel<<<256, 512, 0, stream>>>(zn, sumexp, pos, ticket, out);
}

// Round 17
// 90.268 us; speedup vs baseline: 1.3429x; 1.3429x over previous
//
#include <hip/hip_runtime.h>
#include <hip/hip_bf16.h>
#include <stdint.h>
#include <stddef.h>

// NT-Xent loss, B=4096, D=256, N=8192, T=0.5.
// normalize(+zero sumexp/out) -> fused symmetric ZZ^T GEMM + exp
// row/col-sum + positive capture -> 32-block finalize/mean. No NxN.
//
// R21 = R19 FINAL (measured best: 90.02 us). R20's ticket-fused finalize
// REGRESSED +26 us (simexp 40->66 us, first direct measurement): the
// per-thread __threadfence() is an agent-scope release on non-coherent
// per-XCD L2s -> L2 writeback/invalidate per wave, same hardware reason
// R17's grid.sync cost ~40 us. Both cross-block fusion routes are dead on
// this chip. Session evidence summary:
//  - core frozen at R14 geometry: five structural attacks all null
//    (R12 8-barriers, R15 counted-vmcnt+LDS-colsum, R16 2x4+VGPR-unlock,
//    R18 4 waves/SIMD, R13 deferred-epilogue -> spill); simexp ~40 us,
//    MFMA-busy ~6.5 us, latency-bound at every tested configuration.
//  - non-core harvested: reduce 1->32 blocks, prologue vmcnt(8),
//    exp-scale folded into normalize (R19: 92.08 -> 90.02).
//  - remaining wall: ~44 us harness poison-fill (outside kernel_launch),
//    untouchable from here.
// Core: 8 waves in 4x2 (wave = 32r x 64c), af[2][8] LDS-bounce-pinned,
// quadrant phases with deferred epilogue slices (q3 carried one tile),
// 1 __syncthreads/tile, XOR-swizzled LDS (swizzle on global source),
// symmetry (2080 unordered 128x128 tile-pairs: row-sums to rows(ri),
// col-sums to rows(ct), diag s=0 row-only), balanced tail (s=32 halves
// on cj2/cj3), e = exp2(dot'), pos = dot'*ln2.

#define B_ROWS 4096
#define D_DIM  256
#define N_ROWS 8192
#define BM 128
#define BN 128

typedef __bf16 bf16;
typedef bf16  bf16x8  __attribute__((ext_vector_type(8)));
typedef bf16  bf16x4  __attribute__((ext_vector_type(4)));
typedef float floatx4 __attribute__((ext_vector_type(4)));

// ---------------------------------------------------------------- normalize
// One wave per row: 256 fp32 -> L2-normalized bf16 scaled by sqrt(2/ln2)
// so dot' = (2/ln2)*dot and e = exp2(dot'). Zeroes sumexp; zeroes out[0].
__global__ __launch_bounds__(256) void normalize_kernel(
    const float* __restrict__ z_i, const float* __restrict__ z_j,
    bf16* __restrict__ zn, float* __restrict__ sumexp,
    float* __restrict__ out) {
  const int wave = threadIdx.x >> 6;
  const int lane = threadIdx.x & 63;
  const int row  = blockIdx.x * 4 + wave;
  if (blockIdx.x == 0 && threadIdx.x == 0) out[0] = 0.f;
  const float* src = (row < B_ROWS) ? (z_i + (size_t)row * D_DIM)
                                    : (z_j + (size_t)(row - B_ROWS) * D_DIM);
  float4 v = ((const float4*)src)[lane];
  float ss = v.x * v.x + v.y * v.y + v.z * v.z + v.w * v.w;
  #pragma unroll
  for (int m = 1; m < 64; m <<= 1) ss += __shfl_xor(ss, m);
  const float rn = rsqrtf(ss) * 1.6986436f;  // * sqrt(2/ln2)
  bf16x4 o;
  o[0] = (bf16)(v.x * rn);
  o[1] = (bf16)(v.y * rn);
  o[2] = (bf16)(v.z * rn);
  o[3] = (bf16)(v.w * rn);
  ((bf16x4*)(zn + (size_t)row * D_DIM))[lane] = o;
  if (lane == 0) sumexp[row] = 0.f;
}

// ------------------------------------------------------- fused sim+exp+sum
// Grid: 64 ri x 4 cj = 256 blocks (1/CU by 128 KB LDS). Block (ri,cj): 8
// tiles s=8cj+t; (ri<32, cj>=2) add the j64-half (cj-2) of s=32 (tail).
// 8 waves in 4x2 (wave = 32 rows x 64 cols); quadrant phases (16 cols x
// full K = 16 MFMA), finished quadrant's exp/sum slice overlaps the next
// quadrant's MFMAs; q3 carried one tile. LDS XOR-swizzled (swizzle on the
// GLOBAL source address; LDS dest linear).
__global__ __launch_bounds__(512, 2) void simexp_kernel(
    const bf16* __restrict__ zn, float* __restrict__ sumexp,
    float* __restrict__ pos) {
  __shared__ __align__(16) bf16 Bs[2][BN * D_DIM];  // 2 x 64 KB

  const int tid   = threadIdx.x;
  const int wave  = tid >> 6;
  const int lane  = tid & 63;
  const int lcol  = lane & 15;   // MFMA: A row / B col / C col
  const int lquad = lane >> 4;   // MFMA: k-group / C row-group
  const int wr = (wave >> 1) * 32;  // wave row offset: 0,32,64,96
  const int wc = (wave & 1) * 64;   // wave col offset: 0,64
  const int ri = blockIdx.x >> 2;   // row tile 0..63
  const int cj = blockIdx.x & 3;    // s-chunk 0..3
  const int row_base = ri * BM;
  const bool has_tail = (ri < 32 && cj >= 2);

  auto ct_of = [&](int t) { return (ri + 8 * cj + t) & 63; };  // col tile

  // stage rows of a tile into Bs[buf]: chunk slot s=it*512+tid, row n=s>>5,
  // swizzled k-chunk; coalesced 16B global_load_lds, source pre-swizzled.
  auto stageB = [&](int buf, const bf16* src, int it0, int it1) {
    for (int it = it0; it < it1; ++it) {
      const int s   = it * 512 + tid;
      const int n   = s >> 5;
      const int kcs = s & 31;
      const int kc  = (kcs & 24) | ((kcs & 7) ^ (n & 7));
      __builtin_amdgcn_global_load_lds(
          (const __attribute__((address_space(1))) unsigned int*)
              (src + (size_t)n * D_DIM + kc * 8),
          (__attribute__((address_space(3))) unsigned int*)&Bs[buf][s * 8],
          16, 0, 0);
    }
  };

  // ---- prologue: A tile -> buf0, first B tile -> buf1, overlapped.
  stageB(0, zn + (size_t)row_base * D_DIM, 0, 8);
  stageB(1, zn + (size_t)ct_of(0) * BM * D_DIM, 0, 8);
  // af reads only need A: wait A's 8 loads (B0's 8 still in flight).
  asm volatile("s_waitcnt vmcnt(8)" ::: "memory");
  __builtin_amdgcn_sched_barrier(0);
  __builtin_amdgcn_s_barrier();

  // af[ti][kq]: buf0 backing overwritten later -> pinned in registers (64).
  floatx4 af[2][8];
  #pragma unroll
  for (int ti = 0; ti < 2; ++ti) {
    const int n = wr + ti * 16 + lcol;
    #pragma unroll
    for (int kq = 0; kq < 8; ++kq) {
      const int kc  = kq * 4 + lquad;
      const int kcs = (kc & 24) | ((kc & 7) ^ (n & 7));
      af[ti][kq] = *(const floatx4*)(&Bs[0][(n * 32 + kcs) * 8]);
    }
  }
  __syncthreads();  // drains B0 + af reads -> buf0 free for staging

  float rowsum[2][4];  // [ti][r]; row = wr + ti*16 + lquad*4 + r
  #pragma unroll
  for (int ti = 0; ti < 2; ++ti)
    #pragma unroll
    for (int r = 0; r < 4; ++r) rowsum[ti][r] = 0.f;

#define MFMA_(A, B_, C) __builtin_amdgcn_mfma_f32_16x16x32_bf16( \
    __builtin_bit_cast(bf16x8, A), B_, C, 0, 0, 0)

#define QPHASE(ACC, Q)                                                    \
  {                                                                       \
    bf16x8 bfr[8];                                                        \
    const int n = wc + (Q) * 16 + lcol;                                   \
    _Pragma("unroll")                                                     \
    for (int kq = 0; kq < 8; ++kq) {                                      \
      const int kc  = kq * 4 + lquad;                                     \
      const int kcs = (kc & 24) | ((kc & 7) ^ (n & 7));                   \
      bfr[kq] = *(const bf16x8*)(bbase + n * D_DIM + kcs * 8);            \
    }                                                                     \
    ACC[0] = floatx4{0.f, 0.f, 0.f, 0.f};                                 \
    ACC[1] = floatx4{0.f, 0.f, 0.f, 0.f};                                 \
    _Pragma("unroll")                                                     \
    for (int kq = 0; kq < 8; ++kq) {                                      \
      ACC[0] = MFMA_(af[0][kq], bfr[kq], ACC[0]);                         \
      ACC[1] = MFMA_(af[1][kq], bfr[kq], ACC[1]);                         \
    }                                                                     \
  }

#define SLICE(ACC, Q, CB, DG)                                             \
  {                                                                       \
    float cs = 0.f;                                                       \
    _Pragma("unroll")                                                     \
    for (int ti = 0; ti < 2; ++ti) {                                      \
      _Pragma("unroll")                                                   \
      for (int r = 0; r < 4; ++r) {                                       \
        const float v = ACC[ti][r];                                       \
        float e = __builtin_amdgcn_exp2f(v);                              \
        if (DG) {                                                         \
          const int rg = row_base + wr + ti * 16 + lquad * 4 + r;         \
          const int cg = (CB) + wc + (Q) * 16 + lcol;                     \
          if (cg == rg) e = 0.f;  /* mask self-similarity */              \
        }                                                                 \
        rowsum[ti][r] += e;                                               \
        cs += e;                                                          \
      }                                                                   \
    }                                                                     \
    cs += __shfl_xor(cs, 16);                                             \
    cs += __shfl_xor(cs, 32);                                             \
    if (!(DG) && lquad == 0)                                              \
      atomicAdd(&sumexp[(CB) + wc + (Q) * 16 + lcol], cs);                \
  }

  floatx4 a3[2];            // q3 acc, carried one tile (sliced next tile)
  int  pcol3  = 0;
  bool pdiag3 = false;

  #pragma unroll 1
  for (int t = 0; t < 8; ++t) {
    const bf16* bbase = &Bs[(t + 1) & 1][0];   // compute buffer
    const int sb = t & 1;                      // stage buffer (disjoint)
    if (t < 7) {
      stageB(sb, zn + (size_t)ct_of(t + 1) * BM * D_DIM, 0, 8);
    } else if (has_tail) {
      stageB(sb, zn + (size_t)((ri + 32) * BM + (cj - 2) * 64) * D_DIM, 0, 4);
    }
    const int  colb = ct_of(t) * BM;
    const bool diag = (cj == 0 && t == 0);

    floatx4 a0[2], a1[2], a2[2];
    QPHASE(a0, 0)
    if (t > 0) SLICE(a3, 3, pcol3, pdiag3)   // prev tile's q3, overlapped
    QPHASE(a1, 1)
    SLICE(a0, 0, colb, diag)
    QPHASE(a2, 2)
    SLICE(a1, 1, colb, diag)
    QPHASE(a3, 3)
    SLICE(a2, 2, colb, diag)
    pcol3 = colb;
    pdiag3 = diag;
    __syncthreads();  // vmcnt(0)+barrier: stage done, buffer swap safe
  }
  SLICE(a3, 3, pcol3, pdiag3)   // tile 7's q3

  // tail: j64-half (cj-2) of s=32 in buf1; positive pairs live here.
  if (has_tail && wc == 0) {
    const int colb = (ri + 32) * BM + (cj - 2) * 64;
    const bf16* bbase = &Bs[1][0];
    floatx4 ta[2];
    #pragma unroll
    for (int Q = 0; Q < 4; ++Q) {
      QPHASE(ta, Q)
      float cs = 0.f;
      #pragma unroll
      for (int ti = 0; ti < 2; ++ti) {
        #pragma unroll
        for (int r = 0; r < 4; ++r) {
          const float v = ta[ti][r];
          const float e = __builtin_amdgcn_exp2f(v);
          const int rg = row_base + wr + ti * 16 + lquad * 4 + r;
          const int cg = colb + Q * 16 + lcol;
          if (cg == rg + B_ROWS) {                    // positive pair
            const float p = v * 0.6931471805599453f;  // sim/T = v*ln2
            pos[rg] = p;
            pos[cg] = p;
          }
          rowsum[ti][r] += e;
          cs += e;
        }
      }
      cs += __shfl_xor(cs, 16);
      cs += __shfl_xor(cs, 32);
      if (lquad == 0) atomicAdd(&sumexp[colb + Q * 16 + lcol], cs);
    }
  }
#undef SLICE
#undef QPHASE
#undef MFMA_

  // rowsum: reduce 16 col-lanes, 1 atomic per row per wave
  #pragma unroll
  for (int ti = 0; ti < 2; ++ti) {
    #pragma unroll
    for (int r = 0; r < 4; ++r) {
      float s2 = rowsum[ti][r];
      s2 += __shfl_xor(s2, 1);
      s2 += __shfl_xor(s2, 2);
      s2 += __shfl_xor(s2, 4);
      s2 += __shfl_xor(s2, 8);
      if (lcol == 0) {
        const int grow = row_base + wr + ti * 16 + lquad * 4 + r;
        atomicAdd(&sumexp[grow], s2);
      }
    }
  }
}

// ------------------------------------------- finalize + mean (32 blocks)
// loss_k = log(sumexp_k) - pos_k ; out += block_partial / N.
__global__ __launch_bounds__(256) void reduce_kernel(
    const float* __restrict__ sumexp, const float* __restrict__ pos,
    float* __restrict__ out) {
  __shared__ float ws[4];
  const int tid = threadIdx.x;
  const int k = blockIdx.x * 256 + tid;
  const float ln2 = 0.6931471805599453f;
  float s = __builtin_amdgcn_logf(sumexp[k]) * ln2 - pos[k];
  #pragma unroll
  for (int m = 1; m < 64; m <<= 1) s += __shfl_xor(s, m);
  const int wave = tid >> 6, lane = tid & 63;
  if (lane == 0) ws[wave] = s;
  __syncthreads();
  if (tid == 0) {
    const float t = ws[0] + ws[1] + ws[2] + ws[3];
    atomicAdd(out, t * (1.0f / N_ROWS));
  }
}

extern "C" void kernel_launch(void* const* d_in, const int* in_sizes, int n_in,
                              void* d_out, int out_size, void* d_ws,
                              size_t ws_size, hipStream_t stream) {
  const float* z_i = (const float*)d_in[0];
  const float* z_j = (const float*)d_in[1];
  float* out = (float*)d_out;

  // workspace layout: zn (4 MB bf16) | sumexp (32 KB) | pos (32 KB)
  bf16* zn = (bf16*)d_ws;
  float* sumexp = (float*)((char*)d_ws + (size_t)N_ROWS * D_DIM * sizeof(bf16));
  float* pos = sumexp + N_ROWS;

  normalize_kernel<<<N_ROWS / 4, 256, 0, stream>>>(z_i, z_j, zn, sumexp, out);
  simexp_kernel<<<256, 512, 0, stream>>>(zn, sumexp, pos);
  reduce_kernel<<<32, 256, 0, stream>>>(sumexp, pos, out);
}